// Round 12
// baseline (71.990 us; speedup 1.0000x reference)
//
#include <hip/hip_runtime.h>
#include <math.h>

#define S_IMG 160
#define NPIX (S_IMG * S_IMG)   // 25600
#define NF 4096
#define NV 1986                // vertices in the uv-sphere
#define TS 16                  // tile size 16x16
#define NTX 10                 // tiles per row
#define NTILE 100
#define CAP NF                 // per-tile survivor capacity (faces)
#define MAXK 64                // max 64-face chunks per tile
#define NBLK 512               // cover blocks (4 waves each -> 2048 waves)
#define INV_LN2 1.4426950408889634f
#define CULL_THRESH -25.0f     // 2^d < 2^-25 => fma(P,e,P) == P bitwise (P>=1)

#define ROT_EPS 6.123234e-17f
#define CAM_Z 2.732f
#define VIEW_TAN 0.5773502691896258f

#if __has_builtin(__builtin_amdgcn_exp2f)
#define EXP2F(x) __builtin_amdgcn_exp2f(x)
#else
#define EXP2F(x) exp2f(x)
#endif

// K1: one block per 16x16 tile. Project verts to LDS, cull + ordered ballot
// compaction of 9 edge coefficients (pre-scaled by log2 e), pad to a
// 64-multiple with dummy faces (dmin=-64 -> e=2^-64: bitwise no-op on
// fma(P,e,P) for all finite P>=1, inf-safe).
__global__ void __launch_bounds__(512) setup_cull(const float* __restrict__ verts,
                                                  const int* __restrict__ faces,
                                                  float* __restrict__ list,
                                                  int* __restrict__ nk_arr) {
    __shared__ float2 sverts[NV];
    __shared__ int wcnt[8];

    const int t = blockIdx.x;
    const int tid = threadIdx.x;
    const int wid = tid >> 6;
    const int lane = tid & 63;

    for (int i = tid; i < NV; i += 512) {
        float x = verts[3 * i], y = verts[3 * i + 1], z = verts[3 * i + 2];
        float vx = fmaf(ROT_EPS, x, z);
        float vz = fmaf(ROT_EPS, z, -x) + CAM_Z;
        float inv = __builtin_amdgcn_rcpf(vz * VIEW_TAN);
        sverts[i] = make_float2(fmaf(vx * inv, 80.0f, 80.0f),
                                fmaf(y * inv, 80.0f, 80.0f));
    }
    __syncthreads();

    const float cx = (float)((t % NTX) * TS) + 8.0f;   // centers span +-7.5
    const float cy = (float)((t / NTX) * TS) + 8.0f;
    float* mylist = list + (size_t)t * CAP * 12;
    int base = 0;

    for (int r = 0; r < NF / 512; ++r) {
        int f = r * 512 + tid;
        int i0 = faces[3 * f], i1 = faces[3 * f + 1], i2 = faces[3 * f + 2];
        float2 a = sverts[i0];
        float2 b = sverts[i1];
        float2 c = sverts[i2];
        float area = (b.x - a.x) * (c.y - a.y) - (b.y - a.y) * (c.x - a.x);
        float sg = (area >= 0.0f) ? INV_LN2 : -INV_LN2;
        bool valid = fabsf(area) > 1e-6f;

        float o[9];
        float umin = 1e30f;
        float2 p0s[3] = {a, b, c};
        float2 p1s[3] = {b, c, a};
#pragma unroll
        for (int e = 0; e < 3; ++e) {
            float dx = p1s[e].x - p0s[e].x;
            float dy = p1s[e].y - p0s[e].y;
            float dd = fmaf(dx, dx, dy * dy);
            float s = sg * __builtin_amdgcn_rsqf(dd);   // 1/|edge| ~1ulp
            float A = valid ? (-dy * s) : 0.0f;
            float B = valid ? (dx * s) : 0.0f;
            float C = valid ? ((dy * p0s[e].x - dx * p0s[e].y) * s) : -1e30f;
            o[3 * e + 0] = A;
            o[3 * e + 1] = B;
            o[3 * e + 2] = C;
            float bound = fmaf(fabsf(A) + fabsf(B), 7.5f, fmaf(A, cx, fmaf(B, cy, C)));
            umin = fminf(umin, valid ? bound : -1e30f);
        }
        bool pred = umin >= CULL_THRESH;
        unsigned long long m = __ballot(pred);
        int wpop = __popcll(m);
        int prefix = __popcll(m & ((1ull << lane) - 1ull));

        __syncthreads();                 // protect wcnt vs previous round
        if (lane == 0) wcnt[wid] = wpop;
        __syncthreads();
        int off = base;
#pragma unroll
        for (int w = 0; w < 8; ++w) {
            int cw = wcnt[w];
            if (w < wid) off += cw;
            base += cw;                  // running total, identical in all threads
        }
        off += prefix;
        if (pred) {
            float4* dst = (float4*)(mylist + (size_t)off * 12);
            dst[0] = make_float4(o[0], o[1], o[2], o[3]);
            dst[1] = make_float4(o[4], o[5], o[6], o[7]);
            dst[2] = make_float4(o[8], 0.0f, 0.0f, 0.0f);
        }
    }
    __syncthreads();

    const int cnt = base;
    const int nkt = (cnt + 63) >> 6;     // 0 allowed (empty tile)
    int padcnt = nkt * 64 - cnt;
    for (int i = tid; i < padcnt; i += 512) {
        float4* dst = (float4*)(mylist + (size_t)(cnt + i) * 12);
        dst[0] = make_float4(0.0f, 0.0f, -64.0f, 0.0f);
        dst[1] = make_float4(0.0f, -64.0f, 0.0f, 0.0f);
        dst[2] = make_float4(-64.0f, 0.0f, 0.0f, 0.0f);
    }
    if (tid == 0) nk_arr[t] = nkt;
}

// K1b: single tiny block. Serial exclusive scan of nk_arr, then parallel
// emission of the flat item list items[p] = (t<<8)|k in ascending order.
__global__ void __launch_bounds__(128) build_items(const int* __restrict__ nk_arr,
                                                   int* __restrict__ cumk,
                                                   int* __restrict__ items) {
    __shared__ int scum[NTILE + 1];
    if (threadIdx.x == 0) {
        int acc = 0;
        for (int t = 0; t < NTILE; ++t) { scum[t] = acc; acc += nk_arr[t]; }
        scum[NTILE] = acc;
        cumk[NTILE] = acc;
    }
    __syncthreads();
    for (int t = threadIdx.x; t < NTILE; t += 128) {
        int b = scum[t], n = scum[t + 1] - b;
        cumk[t] = b;
        for (int k = 0; k < n; ++k) items[b + k] = (t << 8) | k;
    }
}

// K2: fixed grid NBLK x 256 (4 waves/block). Waves grid-stride the flat item
// list; every item = 64 faces for one tile -> uniform cost. Per item:
// coalesced per-lane stage into the wave's LDS slot, then uniform ds_reads.
__global__ void __launch_bounds__(256) cover(const float* __restrict__ list,
                                             const int* __restrict__ cumk,
                                             const int* __restrict__ items,
                                             float* __restrict__ partials) {
    __shared__ float4 slot[4][64 * 3];   // 12 KB
    const int wid = threadIdx.x >> 6;
    const int lane = threadIdx.x & 63;
    const int NIT = cumk[NTILE];
    const int NW = NBLK * 4;
    float4* myslot = slot[wid];

    for (int p = blockIdx.x * 4 + wid; p < NIT; p += NW) {
        int item = items[p];
        int t = item >> 8, k = item & 255;

        const float4* src = (const float4*)(list + ((size_t)t * CAP + (size_t)k * 64) * 12);
#pragma unroll
        for (int i = 0; i < 3; ++i) myslot[lane + i * 64] = src[lane + i * 64];
        asm volatile("s_waitcnt lgkmcnt(0)" ::: "memory");  // wave-private slot

        const int colL = lane & 15;
        const int rowL = (lane >> 4) * 4;
        const float px = (float)((t % NTX) * TS + colL) + 0.5f;
        const float py0 = (float)((t / NTX) * TS + rowL) + 0.5f;
        const float py1 = py0 + 1.0f, py2 = py0 + 2.0f, py3 = py0 + 3.0f;

        float P0 = 1.0f, P1 = 1.0f, P2 = 1.0f, P3 = 1.0f;
        for (int j = 0; j < 64; ++j) {
            float4 c0 = myslot[3 * j];
            float4 c1 = myslot[3 * j + 1];
            float4 c2 = myslot[3 * j + 2];
            float b1 = fmaf(c0.x, px, c0.z);
            float b2 = fmaf(c0.w, px, c1.y);
            float b3 = fmaf(c1.z, px, c2.x);
            {
                float d1 = fmaf(c0.y, py0, b1), d2 = fmaf(c1.x, py0, b2), d3 = fmaf(c1.w, py0, b3);
                float e = EXP2F(fminf(fminf(d1, d2), d3));
                P0 = fmaf(P0, e, P0);
            }
            {
                float d1 = fmaf(c0.y, py1, b1), d2 = fmaf(c1.x, py1, b2), d3 = fmaf(c1.w, py1, b3);
                float e = EXP2F(fminf(fminf(d1, d2), d3));
                P1 = fmaf(P1, e, P1);
            }
            {
                float d1 = fmaf(c0.y, py2, b1), d2 = fmaf(c1.x, py2, b2), d3 = fmaf(c1.w, py2, b3);
                float e = EXP2F(fminf(fminf(d1, d2), d3));
                P2 = fmaf(P2, e, P2);
            }
            {
                float d1 = fmaf(c0.y, py3, b1), d2 = fmaf(c1.x, py3, b2), d3 = fmaf(c1.w, py3, b3);
                float e = EXP2F(fminf(fminf(d1, d2), d3));
                P3 = fmaf(P3, e, P3);
            }
        }
        asm volatile("" ::: "memory");   // keep reads before next stage overwrite

        size_t base = ((size_t)t * MAXK + k) * 256 + (size_t)rowL * 16 + colL;
        partials[base] = __builtin_amdgcn_rcpf(P0);
        partials[base + 16] = __builtin_amdgcn_rcpf(P1);
        partials[base + 32] = __builtin_amdgcn_rcpf(P2);
        partials[base + 48] = __builtin_amdgcn_rcpf(P3);
    }
}

// K3: one block per tile (256 thr = 256 px). Fixed-k-order product over live
// layers, image + tile SSE (deterministic tree).
__global__ void __launch_bounds__(256) finish(const float* __restrict__ partials,
                                              const int* __restrict__ nk_arr,
                                              const float* __restrict__ img_ref,
                                              float* __restrict__ out,
                                              float* __restrict__ bsums) {
    const int t = blockIdx.x;
    const int tid = threadIdx.x;
    const int nkt = nk_arr[t];
    float prod = 1.0f;
    for (int k = 0; k < nkt; ++k) prod *= partials[((size_t)t * MAXK + k) * 256 + tid];
    float img = 1.0f - prod;
    int col = (t % NTX) * TS + (tid & 15);
    int row = (t / NTX) * TS + (tid >> 4);
    int p = row * S_IMG + col;
    out[p] = img;
    float d = img - img_ref[p];
    float sq = d * d;
#pragma unroll
    for (int off = 32; off > 0; off >>= 1) sq += __shfl_down(sq, off);
    __shared__ float red[4];
    int lane = tid & 63;
    int wid = tid >> 6;
    if (lane == 0) red[wid] = sq;
    __syncthreads();
    if (tid == 0) bsums[t] = (red[0] + red[1]) + (red[2] + red[3]);
}

// K4: fixed-order reduction of 100 tile SSEs -> loss.
__global__ void __launch_bounds__(64) loss_kernel(const float* __restrict__ bsums,
                                                  float* __restrict__ loss_out) {
    int lane = threadIdx.x;
    float v = 0.0f;
    if (lane < NTILE) v = bsums[lane];
    if (lane + 64 < NTILE) v += bsums[lane + 64];
#pragma unroll
    for (int off = 32; off > 0; off >>= 1) v += __shfl_down(v, off);
    if (lane == 0) loss_out[0] = v;
}

extern "C" void kernel_launch(void* const* d_in, const int* in_sizes, int n_in,
                              void* d_out, int out_size, void* d_ws, size_t ws_size,
                              hipStream_t stream) {
    const float* verts = (const float*)d_in[0];
    const int* faces = (const int*)d_in[1];
    const float* img_ref = (const float*)d_in[2];
    float* out = (float*)d_out;

    // workspace layout (16B aligned)
    float* list = (float*)d_ws;                                   // 100*4096*12 f = 19.66 MB
    float* partials = list + (size_t)NTILE * CAP * 12;            // 100*64*256 f = 6.55 MB
    int* nk_arr = (int*)(partials + (size_t)NTILE * MAXK * 256);  // 100
    int* cumk = nk_arr + 128;                                     // 101 (+pad)
    int* items = cumk + 128;                                      // <= 6400
    float* bsums = (float*)(items + NTILE * MAXK + 128);          // 100

    // CALIBRATION EXPERIMENT: run the (idempotent) pipeline TWICE.
    // Every stage recomputes its outputs purely from inputs / earlier stages,
    // so the second pass is bitwise-identical -> output unchanged.
    // dur_us(doubled) - 38.7 isolates the true pipeline GPU cost P:
    //   ~0   -> external ~38.5us floor (max model)   -> roofline
    //   +P   -> additive fixed cost C = 38.7 - P      -> C dominates if P small
    //   +30+ -> kernels genuinely cost ~30+; dig per-kernel next round
    for (int rep = 0; rep < 2; ++rep) {
        setup_cull<<<NTILE, 512, 0, stream>>>(verts, faces, list, nk_arr);
        build_items<<<1, 128, 0, stream>>>(nk_arr, cumk, items);
        cover<<<NBLK, 256, 0, stream>>>(list, cumk, items, partials);
        finish<<<NTILE, 256, 0, stream>>>(partials, nk_arr, img_ref, out, bsums);
        loss_kernel<<<1, 64, 0, stream>>>(bsums, out + NPIX);
    }
}

// Round 13
// 44.879 us; speedup vs baseline: 1.6041x; 1.6041x over previous
//
#include <hip/hip_runtime.h>
#include <math.h>

#define S_IMG 160
#define NPIX (S_IMG * S_IMG)   // 25600
#define NF 4096
#define NV 1986                // vertices in the uv-sphere
// cull tiles: 16 wide x 32 tall -> 10 x 5 = 50 tiles of 512 px
#define NTTX 10
#define NTILE2 50
#define CAP NF                 // per-tile survivor capacity (faces)
#define MAXK 64                // 64-face chunks per tile (cap 4096/64)
#define NBLK3 800              // cover blocks x 4 waves = 3200 waves = 50*64 items
#define INV_LN2 1.4426950408889634f
#define CULL_THRESH -25.0f     // 2^d < 2^-25 => fma(P,e,P) == P bitwise (P>=1)

#define ROT_EPS 6.123234e-17f
#define CAM_Z 2.732f
#define VIEW_TAN 0.5773502691896258f

#if __has_builtin(__builtin_amdgcn_exp2f)
#define EXP2F(x) __builtin_amdgcn_exp2f(x)
#else
#define EXP2F(x) exp2f(x)
#endif

// K1: one block (1024 thr) per 16x32 tile. Project verts to LDS, cull +
// ordered ballot-compaction. Packed layout: per face 2 float4 (A1,B1,C1,A2 |
// B2,C2,A3,B3) + 1 float (C3) -> 2 ds_read_b128 + 1 ds_read_b32 in cover.
// Pad to 64-multiple with dummies (C*=-64 -> e=2^-64: bitwise no-op on
// fma(P,e,P) for all finite P>=1, inf-safe).
__global__ void __launch_bounds__(1024) setup_cull(const float* __restrict__ verts,
                                                   const int* __restrict__ faces,
                                                   float4* __restrict__ qlist,
                                                   float* __restrict__ c3list,
                                                   int* __restrict__ nk_arr) {
    __shared__ float2 sverts[NV];
    __shared__ int wcnt[16];

    const int t = blockIdx.x;
    const int tid = threadIdx.x;
    const int wid = tid >> 6;
    const int lane = tid & 63;

    for (int i = tid; i < NV; i += 1024) {
        float x = verts[3 * i], y = verts[3 * i + 1], z = verts[3 * i + 2];
        float vx = fmaf(ROT_EPS, x, z);
        float vz = fmaf(ROT_EPS, z, -x) + CAM_Z;
        float inv = __builtin_amdgcn_rcpf(vz * VIEW_TAN);
        sverts[i] = make_float2(fmaf(vx * inv, 80.0f, 80.0f),
                                fmaf(y * inv, 80.0f, 80.0f));
    }
    __syncthreads();

    const float cx = (float)((t % NTTX) * 16) + 8.0f;    // half-extent 7.5
    const float cy = (float)((t / NTTX) * 32) + 16.0f;   // half-extent 15.5
    float4* myq = qlist + (size_t)t * CAP * 2;
    float* myc = c3list + (size_t)t * CAP;
    int base = 0;

    for (int r = 0; r < NF / 1024; ++r) {
        int f = r * 1024 + tid;
        int i0 = faces[3 * f], i1 = faces[3 * f + 1], i2 = faces[3 * f + 2];
        float2 a = sverts[i0];
        float2 b = sverts[i1];
        float2 c = sverts[i2];
        float area = (b.x - a.x) * (c.y - a.y) - (b.y - a.y) * (c.x - a.x);
        float sg = (area >= 0.0f) ? INV_LN2 : -INV_LN2;
        bool valid = fabsf(area) > 1e-6f;

        float o[9];
        float umin = 1e30f;
        float2 p0s[3] = {a, b, c};
        float2 p1s[3] = {b, c, a};
#pragma unroll
        for (int e = 0; e < 3; ++e) {
            float dx = p1s[e].x - p0s[e].x;
            float dy = p1s[e].y - p0s[e].y;
            float dd = fmaf(dx, dx, dy * dy);
            float s = sg * __builtin_amdgcn_rsqf(dd);   // 1/|edge| ~1ulp
            float A = valid ? (-dy * s) : 0.0f;
            float B = valid ? (dx * s) : 0.0f;
            float C = valid ? ((dy * p0s[e].x - dx * p0s[e].y) * s) : -1e30f;
            o[3 * e + 0] = A;
            o[3 * e + 1] = B;
            o[3 * e + 2] = C;
            float bound = fmaf(fabsf(A), 7.5f,
                         fmaf(fabsf(B), 15.5f, fmaf(A, cx, fmaf(B, cy, C))));
            umin = fminf(umin, valid ? bound : -1e30f);
        }
        bool pred = umin >= CULL_THRESH;
        unsigned long long m = __ballot(pred);
        int wpop = __popcll(m);
        int prefix = __popcll(m & ((1ull << lane) - 1ull));

        __syncthreads();                 // protect wcnt vs previous round
        if (lane == 0) wcnt[wid] = wpop;
        __syncthreads();
        int off = base;
#pragma unroll
        for (int w = 0; w < 16; ++w) {
            int cw = wcnt[w];
            if (w < wid) off += cw;
            base += cw;                  // running total, identical in all threads
        }
        off += prefix;
        if (pred) {
            myq[(size_t)off * 2] = make_float4(o[0], o[1], o[2], o[3]);
            myq[(size_t)off * 2 + 1] = make_float4(o[4], o[5], o[6], o[7]);
            myc[off] = o[8];
        }
    }
    __syncthreads();

    const int cnt = base;
    const int nkt = (cnt + 63) >> 6;     // 0 allowed (empty tile)
    int padcnt = nkt * 64 - cnt;
    for (int i = tid; i < padcnt; i += 1024) {
        myq[(size_t)(cnt + i) * 2] = make_float4(0.0f, 0.0f, -64.0f, 0.0f);
        myq[(size_t)(cnt + i) * 2 + 1] = make_float4(0.0f, -64.0f, 0.0f, 0.0f);
        myc[cnt + i] = -64.0f;
    }
    if (tid == 0) nk_arr[t] = nkt;
}

// K2: grid 800 x 256 = 3200 waves; wave gw owns virtual item p = gw:
// t = p>>6, k = p&63; dead items (k >= nk[t]) exit immediately. No scan, no
// atomics, perfect 1-item/wave balance. Per item: stage 64 faces (2 float4 +
// 1 float per lane, coalesced) into the wave's LDS slot; 16x32-px tile =
// 8 px/lane -> the 3 broadcast DS reads per face serve 512 pixels.
__global__ void __launch_bounds__(256) cover(const float4* __restrict__ qlist,
                                             const float* __restrict__ c3list,
                                             const int* __restrict__ nk_arr,
                                             float* __restrict__ partials) {
    __shared__ float4 sq[4][128];
    __shared__ float sc[4][64];
    const int wid = threadIdx.x >> 6;
    const int lane = threadIdx.x & 63;
    const int p = blockIdx.x * 4 + wid;
    const int t = p >> 6;
    const int k = p & 63;
    if (k >= nk_arr[t]) return;

    {
        const float4* srcq = qlist + ((size_t)t * CAP + (size_t)k * 64) * 2;
        const float* srcc = c3list + (size_t)t * CAP + (size_t)k * 64;
        sq[wid][lane * 2] = srcq[lane * 2];
        sq[wid][lane * 2 + 1] = srcq[lane * 2 + 1];
        sc[wid][lane] = srcc[lane];
    }
    asm volatile("s_waitcnt lgkmcnt(0)" ::: "memory");  // wave-private slot

    const int colL = lane & 15;
    const int rowB = (lane >> 4) * 8;        // 4 groups x 8 rows = 32 rows
    const float px = (float)((t % NTTX) * 16 + colL) + 0.5f;
    const float py0 = (float)((t / NTTX) * 32 + rowB) + 0.5f;

    float P0 = 1.0f, P1 = 1.0f, P2 = 1.0f, P3 = 1.0f;
    float P4 = 1.0f, P5 = 1.0f, P6 = 1.0f, P7 = 1.0f;

    for (int j = 0; j < 64; ++j) {
        float4 q0 = sq[wid][2 * j];
        float4 q1 = sq[wid][2 * j + 1];
        float c3 = sc[wid][j];
        // A1=q0.x B1=q0.y C1=q0.z A2=q0.w | B2=q1.x C2=q1.y A3=q1.z B3=q1.w | C3=c3
        float b1 = fmaf(q0.x, px, q0.z);
        float b2 = fmaf(q0.w, px, q1.y);
        float b3 = fmaf(q1.z, px, c3);
#define ROW(rr, PP)                                                            \
        {                                                                      \
            float py = py0 + (float)(rr);                                      \
            float d1 = fmaf(q0.y, py, b1);                                     \
            float d2 = fmaf(q1.x, py, b2);                                     \
            float d3 = fmaf(q1.w, py, b3);                                     \
            float e = EXP2F(fminf(fminf(d1, d2), d3));                         \
            PP = fmaf(PP, e, PP);                                              \
        }
        ROW(0, P0) ROW(1, P1) ROW(2, P2) ROW(3, P3)
        ROW(4, P4) ROW(5, P5) ROW(6, P6) ROW(7, P7)
#undef ROW
    }

    size_t base = ((size_t)t * MAXK + k) * 512 + (size_t)rowB * 16 + colL;
    partials[base] = __builtin_amdgcn_rcpf(P0);
    partials[base + 16] = __builtin_amdgcn_rcpf(P1);
    partials[base + 32] = __builtin_amdgcn_rcpf(P2);
    partials[base + 48] = __builtin_amdgcn_rcpf(P3);
    partials[base + 64] = __builtin_amdgcn_rcpf(P4);
    partials[base + 80] = __builtin_amdgcn_rcpf(P5);
    partials[base + 96] = __builtin_amdgcn_rcpf(P6);
    partials[base + 112] = __builtin_amdgcn_rcpf(P7);
}

// K3: one block per tile (512 thr = 512 px). Fixed-k-order product over live
// layers, image + tile SSE (deterministic tree).
__global__ void __launch_bounds__(512) finish(const float* __restrict__ partials,
                                              const int* __restrict__ nk_arr,
                                              const float* __restrict__ img_ref,
                                              float* __restrict__ out,
                                              float* __restrict__ bsums) {
    const int t = blockIdx.x;
    const int tid = threadIdx.x;
    const int nkt = nk_arr[t];
    float prod = 1.0f;
#pragma unroll 4
    for (int k = 0; k < nkt; ++k) prod *= partials[((size_t)t * MAXK + k) * 512 + tid];
    float img = 1.0f - prod;
    int col = (t % NTTX) * 16 + (tid & 15);
    int row = (t / NTTX) * 32 + (tid >> 4);
    int p = row * S_IMG + col;
    out[p] = img;
    float d = img - img_ref[p];
    float sq = d * d;
#pragma unroll
    for (int off = 32; off > 0; off >>= 1) sq += __shfl_down(sq, off);
    __shared__ float red[8];
    int lane = tid & 63;
    int wid = tid >> 6;
    if (lane == 0) red[wid] = sq;
    __syncthreads();
    if (tid == 0)
        bsums[t] = ((red[0] + red[1]) + (red[2] + red[3])) +
                   ((red[4] + red[5]) + (red[6] + red[7]));
}

// K4: fixed-order reduction of 50 tile SSEs -> loss.
__global__ void __launch_bounds__(64) loss_kernel(const float* __restrict__ bsums,
                                                  float* __restrict__ loss_out) {
    int lane = threadIdx.x;
    float v = 0.0f;
    if (lane < NTILE2) v = bsums[lane];
#pragma unroll
    for (int off = 32; off > 0; off >>= 1) v += __shfl_down(v, off);
    if (lane == 0) loss_out[0] = v;
}

extern "C" void kernel_launch(void* const* d_in, const int* in_sizes, int n_in,
                              void* d_out, int out_size, void* d_ws, size_t ws_size,
                              hipStream_t stream) {
    const float* verts = (const float*)d_in[0];
    const int* faces = (const int*)d_in[1];
    const float* img_ref = (const float*)d_in[2];
    float* out = (float*)d_out;

    // workspace layout (16B aligned)
    float4* qlist = (float4*)d_ws;                                  // 50*4096*2 f4 = 6.55 MB
    float* c3list = (float*)(qlist + (size_t)NTILE2 * CAP * 2);     // 50*4096 f   = 0.82 MB
    float* partials = c3list + (size_t)NTILE2 * CAP;                // 50*64*512 f = 6.55 MB
    int* nk_arr = (int*)(partials + (size_t)NTILE2 * MAXK * 512);   // 50 (+pad)
    float* bsums = (float*)(nk_arr + 128);                          // 50

    setup_cull<<<NTILE2, 1024, 0, stream>>>(verts, faces, qlist, c3list, nk_arr);
    cover<<<NBLK3, 256, 0, stream>>>(qlist, c3list, nk_arr, partials);
    finish<<<NTILE2, 512, 0, stream>>>(partials, nk_arr, img_ref, out, bsums);
    loss_kernel<<<1, 64, 0, stream>>>(bsums, out + NPIX);
}